// Round 8
// baseline (240.029 us; speedup 1.0000x reference)
//
#include <hip/hip_runtime.h>

typedef __bf16 bf16x8 __attribute__((ext_vector_type(8)));
typedef float f32x4 __attribute__((ext_vector_type(4)));
typedef unsigned short u16x4 __attribute__((ext_vector_type(4)));
typedef unsigned short u16x8 __attribute__((ext_vector_type(8)));
typedef unsigned int u32x4 __attribute__((ext_vector_type(4)));

__device__ __forceinline__ float bf2f(unsigned short h) {
    union { unsigned int u; float f; } v;
    v.u = ((unsigned int)h) << 16;
    return v.f;
}
__device__ __forceinline__ unsigned short f2bf(float f) {
    return __builtin_bit_cast(unsigned short, (__bf16)f);  // native v_cvt, RNE
}
// async global->LDS, 16B per lane; LDS dest = wave-uniform base + lane*16
__device__ __forceinline__ void glds16(const unsigned short* g, unsigned short* l) {
    __builtin_amdgcn_global_load_lds((__attribute__((address_space(1))) void*)g,
                                     (__attribute__((address_space(3))) void*)l,
                                     16, 0, 0);
}

#define MFMA16(a, b, c) __builtin_amdgcn_mfma_f32_16x16x32_bf16((a), (b), (c), 0, 0, 0)

// ---------------------------------------------------------------------------
// prep1: X f32->bf16 cvt (blocks 0..4095) + merged Wq|Wk|Wv f32->bf16
// transpose into wqkvT[3072][2048] (blocks 4096..10239)
// ---------------------------------------------------------------------------
__global__ __launch_bounds__(256) void prep1(const float* __restrict__ X,
                                             const float* __restrict__ Wq,
                                             const float* __restrict__ Wk,
                                             const float* __restrict__ Wv,
                                             unsigned short* __restrict__ Xbf,
                                             unsigned short* __restrict__ wqkvT) {
    const int b = blockIdx.x;
    const int tid = threadIdx.x;
    if (b < 4096) {
        const int i = (b * 256 + tid) * 4;
        const float4 v = *(const float4*)(X + i);
        u16x4 o;
        o[0] = f2bf(v.x); o[1] = f2bf(v.y); o[2] = f2bf(v.z); o[3] = f2bf(v.w);
        *(u16x4*)(Xbf + i) = o;
        return;
    }
    __shared__ __align__(16) unsigned short tile[32][33];
    const int tx = tid & 31, ty = tid >> 5;
    const int b2 = b - 4096;
    const int kb = (b2 & 63) * 32;   // k-dim base (rows of W)
    const int nb = (b2 >> 6) * 32;   // fused out-col base 0..3071
    const float* src; int scol, sld;
    if (nb < 2048)      { src = Wq; scol = nb;        sld = 2048; }
    else if (nb < 2560) { src = Wk; scol = nb - 2048; sld = 512;  }
    else                { src = Wv; scol = nb - 2560; sld = 512;  }
#pragma unroll
    for (int i = 0; i < 32; i += 8)
        tile[ty + i][tx] = f2bf(src[(size_t)(kb + ty + i) * sld + (scol + tx)]);
    __syncthreads();
#pragma unroll
    for (int i = 0; i < 32; i += 8)
        wqkvT[(size_t)(nb + ty + i) * 2048 + (kb + tx)] = tile[tx][ty + i];
}

// ---------------------------------------------------------------------------
// prep2 (post-QKV GEMM): Wo f32->bf16 transpose -> woT (blocks 0..4095)
// + V bf16 transpose qkv[:,2560:3072] -> vt[512][2048] (blocks 4096..5119)
// ---------------------------------------------------------------------------
__global__ __launch_bounds__(256) void prep2(const float* __restrict__ Wo,
                                             const unsigned short* __restrict__ qkv,
                                             unsigned short* __restrict__ woT,
                                             unsigned short* __restrict__ vt) {
    const int b = blockIdx.x;
    const int tid = threadIdx.x;
    const int tx = tid & 31, ty = tid >> 5;
    __shared__ __align__(16) unsigned short tile[32][33];
    if (b < 4096) {
        const int kb = (b & 63) * 32;
        const int nb = (b >> 6) * 32;
#pragma unroll
        for (int i = 0; i < 32; i += 8)
            tile[ty + i][tx] = f2bf(Wo[(size_t)(kb + ty + i) * 2048 + (nb + tx)]);
        __syncthreads();
#pragma unroll
        for (int i = 0; i < 32; i += 8)
            woT[(size_t)(nb + ty + i) * 2048 + (kb + tx)] = tile[tx][ty + i];
    } else {
        const int b2 = b - 4096;
        const int bx = (b2 & 15) * 32;   // d-col base in V (0..511)
        const int by = (b2 >> 4) * 32;   // s-row base (0..2047)
#pragma unroll
        for (int i = 0; i < 32; i += 8)
            tile[ty + i][tx] = qkv[(size_t)(by + ty + i) * 3072 + 2560 + bx + tx];
        __syncthreads();
#pragma unroll
        for (int i = 0; i < 32; i += 8)
            vt[(size_t)(bx + ty + i) * 2048 + (by + tx)] = tile[tx][ty + i];
    }
}

// ---------------------------------------------------------------------------
// GEMM: C[M][N] = A[M][K] @ BT[N][K]^T (bf16 in, fp32 accum), m97 structure,
// BK=128. Tile BM x 128, 4 waves; BM=128 -> 64x64 wave tiles (best DS ratio),
// BM=64 -> 32x64 (more blocks). global_load_lds width-16 + XOR chunk swizzle.
// ROPE: apply rotary embedding in epilogue for cols < 2560 (QKV GEMM).
// ---------------------------------------------------------------------------
template <int BM, bool ROPE>
__global__ __launch_bounds__(256) void gemm_bt(const unsigned short* __restrict__ A,
                                               const unsigned short* __restrict__ BT,
                                               void* __restrict__ Cv,
                                               int K, int lda, int ldb, int ldc,
                                               int out_f32) {
    constexpr int MT = BM / 32;
    constexpr int ACALLS = BM / 16;   // 4KB-chunks for A tile
    __shared__ __align__(16) unsigned short As[BM * 128];
    __shared__ __align__(16) unsigned short Bs[128 * 128];

    const int tid = threadIdx.x;
    const int lane = tid & 63;
    const int wave = tid >> 6;
    const int quad = lane >> 4;
    const int l15 = lane & 15;
    const int bm = blockIdx.x * BM;
    const int bn = blockIdx.y * 128;
    const int wm = (wave & 1) * (BM / 2);
    const int wn = (wave >> 1) * 64;

    // staging: call i covers rows 16i..16i+16; lane row-in-call = wave*4 + (lane>>4)
    const int srow = wave * 4 + (lane >> 4);          // 0..15
    const int sw = (lane & 15) ^ (srow & 7);          // swizzled chunk 0..15
    const unsigned short* Ag = A + (size_t)(bm + srow) * lda + sw * 8;
    const unsigned short* Bg = BT + (size_t)(bn + srow) * ldb + sw * 8;
    unsigned short* Asl = As + wave * 512;            // + i*2048 per call
    unsigned short* Bsl = Bs + wave * 512;

    f32x4 acc[MT][4] = {};

    for (int k0 = 0; k0 < K; k0 += 128) {
#pragma unroll
        for (int i = 0; i < ACALLS; i++)
            glds16(Ag + (size_t)(16 * i) * lda + k0, Asl + i * 2048);
#pragma unroll
        for (int i = 0; i < 8; i++)
            glds16(Bg + (size_t)(16 * i) * ldb + k0, Bsl + i * 2048);
        __syncthreads();
#pragma unroll
        for (int ks = 0; ks < 4; ks++) {
            bf16x8 af[MT], bfr[4];
#pragma unroll
            for (int mt = 0; mt < MT; mt++) {
                const int row = wm + 16 * mt + l15;
                af[mt] = __builtin_bit_cast(bf16x8,
                    *(const u32x4*)&As[row * 128 + (((quad + 4 * ks) ^ (row & 7)) * 8)]);
            }
#pragma unroll
            for (int nt = 0; nt < 4; nt++) {
                const int row = wn + 16 * nt + l15;
                bfr[nt] = __builtin_bit_cast(bf16x8,
                    *(const u32x4*)&Bs[row * 128 + (((quad + 4 * ks) ^ (row & 7)) * 8)]);
            }
#pragma unroll
            for (int mt = 0; mt < MT; mt++)
#pragma unroll
                for (int nt = 0; nt < 4; nt++)
                    acc[mt][nt] = MFMA16(af[mt], bfr[nt], acc[mt][nt]);
        }
        __syncthreads();
    }

    // fused RoPE on fp32 accumulators (cols < 2560 = Q|K), pairwise via shfl
    if (ROPE) {
#pragma unroll
        for (int mt = 0; mt < MT; mt++) {
#pragma unroll
            for (int nt = 0; nt < 4; nt++) {
                const int col = bn + wn + 16 * nt + l15;
                if (col < 2560) {  // 16-aligned boundary -> wave-uniform branch
                    const int i = (col & 63) >> 1;
                    const float inv = exp2f(-0.41524101186092036f * (float)i);
                    const float sign = (col & 1) ? 1.0f : -1.0f;
#pragma unroll
                    for (int r = 0; r < 4; r++) {
                        const int row = bm + wm + 16 * mt + quad * 4 + r;
                        float sn, cs;
                        __sincosf((float)row * inv, &sn, &cs);
                        const float partner = __shfl_xor(acc[mt][nt][r], 1, 64);
                        acc[mt][nt][r] = acc[mt][nt][r] * cs + sign * partner * sn;
                    }
                }
            }
        }
    }

    // epilogue: C/D layout col = l15, row = quad*4 + r
#pragma unroll
    for (int mt = 0; mt < MT; mt++) {
#pragma unroll
        for (int nt = 0; nt < 4; nt++) {
#pragma unroll
            for (int r = 0; r < 4; r++) {
                const int row = bm + wm + 16 * mt + quad * 4 + r;
                const int col = bn + wn + 16 * nt + l15;
                if (out_f32)
                    ((float*)Cv)[(size_t)row * ldc + col] = acc[mt][nt][r];
                else
                    ((unsigned short*)Cv)[(size_t)row * ldc + col] = f2bf(acc[mt][nt][r]);
            }
        }
    }
}

// ---------------------------------------------------------------------------
// Flash attention, S^T-trick + fixed-max softmax + MFMA row-sum (P @ ones).
// Block = (128 q rows, head); 4 waves, wave owns 32 q rows (2 m-tiles).
// BK=128 KV staging. P buffer stride-64 with XOR chunk swizzle:
//   store b64: chunk (2n+(quad>>1))^(l15&7), offset (quad&1)*4
//   read  b128: chunk (half*4+quad)^(l15&7)
// qkv: [2048][3072] bf16 (Q|K|V, RoPE applied); vt: [512][2048] = V^T.
// ---------------------------------------------------------------------------
__global__ __launch_bounds__(256) void attn_kernel(const unsigned short* __restrict__ qkv,
                                                   const unsigned short* __restrict__ vt,
                                                   unsigned short* __restrict__ attn_out) {
    const int qb = blockIdx.x;
    const int h = blockIdx.y;
    const int kvh = h >> 2;
    const int tid = threadIdx.x;
    const int lane = tid & 63;
    const int wave = tid >> 6;
    const int quad = lane >> 4;
    const int l15 = lane & 15;
    const int w0 = qb * 128 + wave * 32;

    __shared__ __align__(16) unsigned short Ks[128 * 64];   // K rows x 64 d
    __shared__ __align__(16) unsigned short Vs[64 * 128];   // V^T: 64 d x 128 kv
    __shared__ __align__(16) unsigned short St[4][32][64];  // per-wave P, swizzled
    unsigned short (*Sw)[64] = St[wave];

    // K staging map (64-u16 rows, 8 chunk slots)
    const int srow = wave * 8 + (lane >> 3);
    const int swK = (lane & 7) ^ (srow & 7);
    const unsigned short* Kg = qkv + 2048 + kvh * 64 + swK * 8;  // + (kbase+srow+32i)*3072
    unsigned short* Ksl = Ks + wave * 512;
    // V staging map (128-u16 rows, 16 chunk slots)
    const int vrow = wave * 4 + (lane >> 4);
    const int swV = (lane & 15) ^ (vrow & 7);
    const unsigned short* Vg = vt + (size_t)(kvh * 64 + vrow) * 2048 + swV * 8;  // + 16i*2048 + kbase
    unsigned short* Vsl = Vs + wave * 512;

    // Q fragments (MFMA B-operand: n=q=l15, k=quad*8+j), pre-scaled by 1/8
    bf16x8 qf[2][2];
#pragma unroll
    for (int mt = 0; mt < 2; mt++)
#pragma unroll
        for (int ks = 0; ks < 2; ks++) {
            u32x4 raw = *(const u32x4*)&qkv[(size_t)(w0 + 16 * mt + l15) * 3072 + h * 64 + quad * 8 + 32 * ks];
            u16x8 t = __builtin_bit_cast(u16x8, raw);
#pragma unroll
            for (int j = 0; j < 8; j++) t[j] = f2bf(bf2f(t[j]) * 0.125f);
            qf[mt][ks] = __builtin_bit_cast(bf16x8, t);
        }

    bf16x8 ones;
#pragma unroll
    for (int j = 0; j < 8; j++) ones[j] = (__bf16)1.0f;

    f32x4 acc_o[2][4] = {};
    f32x4 acc_l[2] = {};

    const float LOG2E = 1.44269504088896f;
    const float MB = -17.3123404906676f;  // -12 * log2e

    // P-store / P-read swizzled chunk bases (hoisted)
    const int pchunk_off = (quad & 1) * 4;

    for (int kb2 = 0; kb2 < 16; kb2++) {
        const int kbase = kb2 * 128;
#pragma unroll
        for (int i = 0; i < 4; i++) {
            glds16(Kg + (size_t)(kbase + srow + 32 * i) * 3072, Ksl + i * 2048);
            glds16(Vg + (size_t)(16 * i) * 2048 + kbase, Vsl + i * 2048);
        }
        __syncthreads();

#pragma unroll
        for (int kh = 0; kh < 2; kh++) {
            // S^T = K Q^T : A = K-frag (m=kv), B = Q-frag (n=q)
            f32x4 st[2][4] = {};
#pragma unroll
            for (int n = 0; n < 4; n++) {
                const int row = kh * 64 + 16 * n + l15;
                const bf16x8 kf0 = __builtin_bit_cast(bf16x8,
                    *(const u32x4*)&Ks[row * 64 + ((quad ^ (l15 & 7)) * 8)]);
                const bf16x8 kf1 = __builtin_bit_cast(bf16x8,
                    *(const u32x4*)&Ks[row * 64 + (((quad + 4) ^ (l15 & 7)) * 8)]);
#pragma unroll
                for (int mt = 0; mt < 2; mt++) {
                    st[mt][n] = MFMA16(kf0, qf[mt][0], st[mt][n]);
                    st[mt][n] = MFMA16(kf1, qf[mt][1], st[mt][n]);
                }
            }

            // p = exp2(s*log2e - 12*log2e); lane holds q=l15, kv=16n+quad*4+r
            // -> swizzled b64 store into Sw[q][.]
#pragma unroll
            for (int mt = 0; mt < 2; mt++)
#pragma unroll
                for (int n = 0; n < 4; n++) {
                    u16x4 pk;
#pragma unroll
                    for (int r = 0; r < 4; r++)
                        pk[r] = f2bf(exp2f(fmaf(st[mt][n][r], LOG2E, MB)));
                    const int pc = ((2 * n + (quad >> 1)) ^ (l15 & 7)) * 8 + pchunk_off;
                    *(u16x4*)&Sw[16 * mt + l15][pc] = pk;
                }

            // P A-frags (m=q=l15, k=kv=quad*8+j), swizzled b128 reads
            bf16x8 pf[2][2];
#pragma unroll
            for (int mt = 0; mt < 2; mt++) {
                pf[mt][0] = __builtin_bit_cast(bf16x8,
                    *(const u32x4*)&Sw[16 * mt + l15][(quad ^ (l15 & 7)) * 8]);
                pf[mt][1] = __builtin_bit_cast(bf16x8,
                    *(const u32x4*)&Sw[16 * mt + l15][((4 + quad) ^ (l15 & 7)) * 8]);
            }

            // row sums: acc_l[mt] += P @ ones  (C-rows match acc_o's rows)
#pragma unroll
            for (int mt = 0; mt < 2; mt++) {
                acc_l[mt] = MFMA16(pf[mt][0], ones, acc_l[mt]);
                acc_l[mt] = MFMA16(pf[mt][1], ones, acc_l[mt]);
            }

            // O += P @ V : B = V^T rows (n=d=l15, k=kv)
#pragma unroll
            for (int nt = 0; nt < 4; nt++) {
                const int row = 16 * nt + l15;
                const int c0 = kh * 8 + (quad ^ (l15 & 7));
                const int c1 = kh * 8 + ((quad + 4) ^ (l15 & 7));
                const bf16x8 vf0 = __builtin_bit_cast(bf16x8, *(const u32x4*)&Vs[row * 128 + c0 * 8]);
                const bf16x8 vf1 = __builtin_bit_cast(bf16x8, *(const u32x4*)&Vs[row * 128 + c1 * 8]);
#pragma unroll
                for (int mt = 0; mt < 2; mt++) {
                    acc_o[mt][nt] = MFMA16(pf[mt][0], vf0, acc_o[mt][nt]);
                    acc_o[mt][nt] = MFMA16(pf[mt][1], vf1, acc_o[mt][nt]);
                }
            }
        }
        __syncthreads();
    }

    // epilogue: acc_o and acc_l share lane layout q=quad*4+r (+16mt), d=16nt+l15
#pragma unroll
    for (int mt = 0; mt < 2; mt++) {
        float linv[4];
#pragma unroll
        for (int r = 0; r < 4; r++) linv[r] = 1.0f / acc_l[mt][r];
#pragma unroll
        for (int nt = 0; nt < 4; nt++)
#pragma unroll
            for (int r = 0; r < 4; r++)
                attn_out[(size_t)(w0 + 16 * mt + quad * 4 + r) * 2048 + h * 64 + 16 * nt + l15] =
                    f2bf(acc_o[mt][nt][r] * linv[r]);
    }
}

// ---------------------------------------------------------------------------
extern "C" void kernel_launch(void* const* d_in, const int* in_sizes, int n_in,
                              void* d_out, int out_size, void* d_ws, size_t ws_size,
                              hipStream_t stream) {
    (void)in_sizes; (void)n_in; (void)out_size; (void)ws_size;

    const float* X  = (const float*)d_in[0];
    const float* Wq = (const float*)d_in[1];
    const float* Wk = (const float*)d_in[2];
    const float* Wv = (const float*)d_in[3];
    const float* Wo = (const float*)d_in[4];

    // ws (u16): phase1 Xbf[0..4.19M) wqkvT[4.19M..10.49M)
    //           phase2 vt[0..1.05M) attnO[1.05M..5.24M) woT[5.24M..9.44M)
    // qkv parks in d_out (12.6MB of 16.8MB); final GEMM rewrites d_out in f32.
    unsigned short* ws16  = (unsigned short*)d_ws;
    unsigned short* Xbf   = ws16;
    unsigned short* wqkvT = ws16 + (size_t)4194304;
    unsigned short* qkv   = (unsigned short*)d_out;
    unsigned short* vt    = ws16;
    unsigned short* attnO = ws16 + (size_t)1048576;
    unsigned short* woT   = ws16 + (size_t)5242880;

    // X cvt + Wqkv transpose
    prep1<<<10240, 256, 0, stream>>>(X, Wq, Wk, Wv, Xbf, wqkvT);

    // QKV = X @ [Wq|Wk|Wv] -> bf16 in d_out, RoPE fused (128x128 tiles)
    gemm_bt<128, true><<<dim3(16, 24), 256, 0, stream>>>(Xbf, wqkvT, qkv, 2048, 2048, 2048, 3072, 0);

    // Wo transpose (into dead wqkvT region) + V^T (into dead Xbf region)
    prep2<<<5120, 256, 0, stream>>>(Wo, qkv, woT, vt);

    // attention -> attnO (bf16)
    attn_kernel<<<dim3(16, 32), 256, 0, stream>>>(qkv, vt, attnO);

    // out = attnO @ Wo -> f32 into d_out (64x128 tiles: 512 blocks)
    gemm_bt<64, false><<<dim3(32, 16), 256, 0, stream>>>(attnO, woT, (void*)d_out, 2048, 2048, 2048, 2048, 1);
}